// Round 14
// baseline (830.996 us; speedup 1.0000x reference)
//
#include <hip/hip_runtime.h>
#include <stdint.h>

#define NB 8
#define NP 4096
#define NS 1024
#define NK 64
#define ND 64
#define NH 64
#define NCO 128

#define PPT2 16            // producer: 4 waves x 256 threads x 16 points

// padded K strides (in halves) for conflict-free b128 LDS access
#define K1P 104            // layer1 K: 64 x-ch + 3 xyz + zeros to 96, padded to 104
#define K2P 72             // layer2/3 K: 64, padded to 72

// workspace layout (bytes)
#define WS_WIDX 0          // int[NB*NS] per-step winner index tokens (32 KB)
#define WS_WT   32768      // _Float16 weights (20480 halves = 40 KB)

typedef _Float16 half8v __attribute__((ext_vector_type(8)));
typedef _Float16 half4v __attribute__((ext_vector_type(4)));
typedef _Float16 half2v __attribute__((ext_vector_type(2)));
typedef float    floatx4 __attribute__((ext_vector_type(4)));

// DPP move helper (ctrl must be compile-time constant)
template <int CTRL>
__device__ __forceinline__ float dpp_mov_f32(float x) {
    return __int_as_float(__builtin_amdgcn_update_dpp(
        0, __float_as_int(x), CTRL, 0xf, 0xf, true));
}

// ---------------- Kernel 0: weight transpose + f16 convert ----------------
__global__ __launch_bounds__(64) void wt_kernel(const float* __restrict__ W1,
                                                const float* __restrict__ W2,
                                                const float* __restrict__ W3,
                                                _Float16* __restrict__ wt)
{
    const int j = blockIdx.x;
    const int t = threadIdx.x;
    if (j < 64) {
        for (int k = t; k < K1P; k += 64) {
            float v = 0.f;
            if (k < 64)       v = W1[(3 + k) * 64 + j];
            else if (k < 67)  v = W1[(k - 64) * 64 + j];
            wt[j * K1P + k] = (_Float16)v;
        }
    } else if (j < 128) {
        const int r = j - 64;
        for (int k = t; k < K2P; k += 64) {
            float v = (k < 64) ? W2[k * 64 + r] : 0.f;
            wt[6656 + r * K2P + k] = (_Float16)v;
        }
    } else {
        const int r = j - 128;
        for (int k = t; k < K2P; k += 64) {
            float v = (k < 64) ? W3[k * 128 + r] : 0.f;
            wt[11264 + r * K2P + k] = (_Float16)v;
        }
    }
}

// ---------------- Fused kernel: fps producers + ballq/mlp consumers ----------
// Grid = 256 blocks x 512 threads; all blocks co-resident => spin-wait safe.
// Blocks 0..7: fps, 4 update waves x 16 pts (R13). NEW: winner coords flow
// through cbuf — each lane speculatively reads sp[bi] (own candidate) during
// the DPP reduce; the winner lane writes key+coords pre-barrier; post-barrier
// the 3-compare key tree is mirrored by cndmask selects over the 4 coord
// vectors (no dependent sp[last] read). Bit-exact: cbuf entries ARE sp rows.
// Tokens latched in registers, flushed 16-wide per 16 steps (R10).
// Blocks 8..255: consumers — token spin, single-wave ballq, MFMA mlp, and
// new_xyz written from pos[token] (bit-identical).
__global__ __launch_bounds__(512, 2) void fused_kernel(
        const float* __restrict__ x, const float* __restrict__ pos,
        const float* __restrict__ b1v, const float* __restrict__ b2v,
        const float* __restrict__ b3v,
        const _Float16* __restrict__ wt,
        float* __restrict__ new_xyz, float* __restrict__ out, int* widx)
{
    __shared__ alignas(16) char smem[65728];
    const int tid  = threadIdx.x;
    const int lane = tid & 63;
    const int wv   = tid >> 6;

    if (blockIdx.x < NB) {
        // ================= FPS (4 update waves, cbuf coords) =================
#pragma clang fp contract(off)
        const int b = blockIdx.x;
        float4* sp = (float4*)smem;                               // 64 KB
        unsigned long long* kbuf = (unsigned long long*)(smem + 65536); // [2][4]
        float4* cbuf = (float4*)(smem + 65600);                   // [2][4]

        const float* p = pos + (size_t)b * NP * 3;
        for (int i = tid; i < NP; i += 512) {
            sp[i] = make_float4(p[i * 3 + 0], p[i * 3 + 1], p[i * 3 + 2], 0.0f);
        }
        __syncthreads();

        if (wv >= 4) {
            // barrier companions: one arrival per step, nothing else
            for (int s = 1; s < NS; ++s) __syncthreads();
            return;
        }

        float px[PPT2], py[PPT2], pz[PPT2], md[PPT2];
#pragma unroll
        for (int j = 0; j < PPT2; ++j) {
            float4 v = sp[tid * PPT2 + j];
            px[j] = v.x; py[j] = v.y; pz[j] = v.z;
            md[j] = 1e10f;
        }

        float4 l0 = sp[0];
        float lx = l0.x, ly = l0.y, lz = l0.z;
        if (tid == 0) {   // s=0 token
            __hip_atomic_store(widx + b * NS, 0, __ATOMIC_RELAXED,
                               __HIP_MEMORY_SCOPE_AGENT);
        }
        int tok = 0;      // per-lane latched token (wave 0 lanes 0..15 flush)

        int par = 0;
        for (int s = 1; s < NS; ++s) {
            float bv = 0.0f;
            int   bi = tid * PPT2;
#pragma unroll
            for (int j = 0; j < PPT2; ++j) {
                float dx = px[j] - lx;
                float dy = py[j] - ly;
                float dz = pz[j] - lz;
                float d2 = dx * dx + dy * dy + dz * dz;  // contract(off): exact
                float m  = (md[j] < d2) ? md[j] : d2;    // jnp.minimum
                md[j] = m;
                if (m > bv) { bv = m; bi = tid * PPT2 + j; }
            }

            // speculative read of own candidate's coords (overlaps DPP reduce)
            float4 spec = sp[bi];

            float r = bv;
            r = fmaxf(r, dpp_mov_f32<0x111>(r));   // row_shr:1
            r = fmaxf(r, dpp_mov_f32<0x112>(r));   // row_shr:2
            r = fmaxf(r, dpp_mov_f32<0x114>(r));   // row_shr:4
            r = fmaxf(r, dpp_mov_f32<0x118>(r));   // row_shr:8
            r = fmaxf(r, dpp_mov_f32<0x142>(r));   // row_bcast:15
            r = fmaxf(r, dpp_mov_f32<0x143>(r));   // row_bcast:31
            const float gmax = __int_as_float(
                __builtin_amdgcn_readlane(__float_as_int(r), 63));

            // first lane achieving gmax = smallest achieving index in wave;
            // that lane writes key + its candidate's coords (== sp[bw] row)
            unsigned long long mk = __ballot(bv == gmax);
            int wl = (int)__builtin_ctzll(mk);
            if (lane == wl) {
                kbuf[par * 4 + wv] =
                    ((unsigned long long)__float_as_uint(bv) << 32) |
                    (unsigned long long)(~(unsigned)bi);
                cbuf[par * 4 + wv] = spec;
            }
            __syncthreads();

            // 4-key tree + mirrored coord selects (broadcast LDS reads)
            const ulonglong2* kb = (const ulonglong2*)(kbuf + par * 4);
            ulonglong2 q0 = kb[0], q1 = kb[1];
            float4 c0 = cbuf[par * 4 + 0], c1 = cbuf[par * 4 + 1];
            float4 c2 = cbuf[par * 4 + 2], c3 = cbuf[par * 4 + 3];
            bool t0 = q0.y > q0.x;
            bool t1 = q1.y > q1.x;
            unsigned long long a0 = t0 ? q0.y : q0.x;
            unsigned long long a1 = t1 ? q1.y : q1.x;
            float ax = t0 ? c1.x : c0.x, ay = t0 ? c1.y : c0.y, az = t0 ? c1.z : c0.z;
            float bx = t1 ? c3.x : c2.x, by = t1 ? c3.y : c2.y, bz = t1 ? c3.z : c2.z;
            bool tg = a1 > a0;
            unsigned long long g = tg ? a1 : a0;
            lx = tg ? bx : ax;
            ly = tg ? by : ay;
            lz = tg ? bz : az;

            const int last = (int)(~(unsigned)g);
            // latch token in the matching lane (all threads know `last`)
            if ((s & 15) == lane) tok = last;
            // flush 16 tokens as one coalesced store per 16 steps
            if ((s & 15) == 15 && wv == 0 && lane < 16) {
                __hip_atomic_store(widx + b * NS + (s - 15) + lane, tok,
                                   __ATOMIC_RELAXED, __HIP_MEMORY_SCOPE_AGENT);
            }
            par ^= 1;
        }
        return;
    }

    // ================= Consumer: ballq + gather + MLP + pool =================
    const int ci = blockIdx.x - NB;   // 0..247
    const int b  = ci & 7;
    const int r0 = ci >> 3;           // 0..30

    _Float16* G   = (_Float16*)smem;            // 64*K1P halves = 13312 B
    _Float16* H1  = (_Float16*)(smem + 13312);  // 64*K2P = 9216 B
    _Float16* H2  = (_Float16*)(smem + 22528);  // 9216 B
    float*    CW  = (float*)(smem + 31744);     // 4*NCO = 2048 B
    float*    Lb  = (float*)(smem + 33792);     // 128 floats = 512 B
    short*  nbr_s = (short*)(smem + 34304);     // 128 B
    float*    qv  = (float*)(smem + 34432);     // 12 B

    const int qd = lane >> 4;         // quad
    const int c  = lane & 15;         // col within MFMA tile
    const int myrow = wv * 16 + c;    // neighbor row (waves 0-3 only)

    // weight frag hoist + bias staging (waves 0-3)
    half8v a1[3][4], a2[2][4], a3[2][8];
    float b3r = 0.f;
    if (tid < 256) {
#pragma unroll
        for (int ks = 0; ks < 3; ++ks)
#pragma unroll
            for (int mt = 0; mt < 4; ++mt)
                a1[ks][mt] = *(const half8v*)&wt[(mt * 16 + c) * K1P + ks * 32 + qd * 8];
#pragma unroll
        for (int ks = 0; ks < 2; ++ks)
#pragma unroll
            for (int mt = 0; mt < 4; ++mt)
                a2[ks][mt] = *(const half8v*)&wt[6656 + (mt * 16 + c) * K2P + ks * 32 + qd * 8];
#pragma unroll
        for (int ks = 0; ks < 2; ++ks)
#pragma unroll
            for (int mt = 0; mt < 8; ++mt)
                a3[ks][mt] = *(const half8v*)&wt[11264 + (mt * 16 + c) * K2P + ks * 32 + qd * 8];
        if (tid < 64) { Lb[tid] = b1v[tid]; Lb[64 + tid] = b2v[tid]; }
        if (tid < NCO) b3r = b3v[tid];
        half8v z = {};
        for (int i = tid; i < (64 * K1P) / 8; i += 256) ((half8v*)G)[i] = z;
    }

    for (int s = r0; s < NS; s += 31) {
        const int bs = b * NS + s;

        // ---- spin on the self-describing token (poison 0xAA.. < 0) ----
        int idx = -1, guard = 0;
        for (;;) {
            idx = __hip_atomic_load(widx + bs, __ATOMIC_RELAXED,
                                    __HIP_MEMORY_SCOPE_AGENT);
            if (idx >= 0) break;
            __builtin_amdgcn_s_sleep(8);
            if (++guard > (1 << 26)) break;   // escape hatch: fail loud, not hang
        }
        const int qidx = (idx >= 0 && idx < NP) ? idx : 0;

        // ---- wave 0: ball query into LDS (query coords from pos[qidx]);
        //      also writes this query's new_xyz (bit-identical to producer's) --
        if (wv == 0) {
#pragma clang fp contract(off)
            const float* p = pos + (size_t)b * NP * 3;
            const float qx = p[qidx * 3 + 0];
            const float qy = p[qidx * 3 + 1];
            const float qz = p[qidx * 3 + 2];
            if (lane == 0) {
                qv[0] = qx; qv[1] = qy; qv[2] = qz;
                float* o = new_xyz + (size_t)bs * 3;
                o[0] = qx; o[1] = qy; o[2] = qz;
            }
            int cnt = 0;
            for (int n0 = 0; n0 < NP; n0 += 64) {
                const int n = n0 + lane;
                float dx = qx - p[n * 3 + 0];
                float dy = qy - p[n * 3 + 1];
                float dz = qz - p[n * 3 + 2];
                float d2 = dx * dx + dy * dy + dz * dz;   // contract(off)
                bool within = d2 < 0.04f;                 // r^2, strict <
                unsigned long long m = __ballot(within);
                if (within) {
                    int slot = cnt + __popcll(m & ((1ull << lane) - 1ull));
                    if (slot < NK) nbr_s[slot] = (short)n;
                }
                cnt += (int)__popcll(m);
                if (cnt >= NK) break;
            }
            if (cnt < NK) {
                if (lane < NK - cnt) nbr_s[cnt + lane] = (short)-1;
            }
        }
        __syncthreads();   // nbr_s, qv ready

        // ---- gather (waves 0-3): thread -> neighbor tid>>2, channel quarter ----
        if (tid < 256) {
            const int ni = tid >> 2;
            const int p4 = tid & 3;
            const int n  = (int)nbr_s[ni];
            const int nn = (n < 0) ? (NP - 1) : n;    // ref: points[-1] padding
            const float* xr = x + ((size_t)b * NP + nn) * ND + p4 * 16;
#pragma unroll
            for (int i = 0; i < 4; ++i) {
                float4 v = *(const float4*)(xr + 4 * i);
                half4v h;
                h[0] = (_Float16)v.x; h[1] = (_Float16)v.y;
                h[2] = (_Float16)v.z; h[3] = (_Float16)v.w;
                *(half4v*)&G[ni * K1P + p4 * 16 + 4 * i] = h;
            }
            if (p4 == 0) {
                const float* pr = pos + (size_t)(b * NP + nn) * 3;
                float gx = pr[0] - qv[0];
                float gy = pr[1] - qv[1];
                float gz = pr[2] - qv[2];
                half2v h2; h2[0] = (_Float16)gx; h2[1] = (_Float16)gy;
                *(half2v*)&G[ni * K1P + 64] = h2;
                G[ni * K1P + 66] = (_Float16)gz;
            }
        }
        __syncthreads();

        if (tid < 256) {
            // ---- layer 1: K=96 (3 steps), out 64 ch ----
            {
                floatx4 acc[4] = {};
#pragma unroll
                for (int ks = 0; ks < 3; ++ks) {
                    half8v bf = *(const half8v*)&G[myrow * K1P + ks * 32 + qd * 8];
#pragma unroll
                    for (int mt = 0; mt < 4; ++mt)
                        acc[mt] = __builtin_amdgcn_mfma_f32_16x16x32_f16(a1[ks][mt], bf, acc[mt], 0, 0, 0);
                }
#pragma unroll
                for (int mt = 0; mt < 4; ++mt) {
                    float4 bb = *(const float4*)&Lb[mt * 16 + qd * 4];
                    half4v h;
                    h[0] = (_Float16)fmaxf(acc[mt][0] + bb.x, 0.f);
                    h[1] = (_Float16)fmaxf(acc[mt][1] + bb.y, 0.f);
                    h[2] = (_Float16)fmaxf(acc[mt][2] + bb.z, 0.f);
                    h[3] = (_Float16)fmaxf(acc[mt][3] + bb.w, 0.f);
                    *(half4v*)&H1[myrow * K2P + mt * 16 + qd * 4] = h;
                }
            }
            // ---- layer 2: K=64 (2 steps), out 64 ch ----
            {
                floatx4 acc[4] = {};
#pragma unroll
                for (int ks = 0; ks < 2; ++ks) {
                    half8v bf = *(const half8v*)&H1[myrow * K2P + ks * 32 + qd * 8];
#pragma unroll
                    for (int mt = 0; mt < 4; ++mt)
                        acc[mt] = __builtin_amdgcn_mfma_f32_16x16x32_f16(a2[ks][mt], bf, acc[mt], 0, 0, 0);
                }
#pragma unroll
                for (int mt = 0; mt < 4; ++mt) {
                    float4 bb = *(const float4*)&Lb[64 + mt * 16 + qd * 4];
                    half4v h;
                    h[0] = (_Float16)fmaxf(acc[mt][0] + bb.x, 0.f);
                    h[1] = (_Float16)fmaxf(acc[mt][1] + bb.y, 0.f);
                    h[2] = (_Float16)fmaxf(acc[mt][2] + bb.z, 0.f);
                    h[3] = (_Float16)fmaxf(acc[mt][3] + bb.w, 0.f);
                    *(half4v*)&H2[myrow * K2P + mt * 16 + qd * 4] = h;
                }
            }
            // ---- layer 3 (swapped operands): C rows = neighbors ----
            {
                floatx4 acc3[8] = {};
#pragma unroll
                for (int ks = 0; ks < 2; ++ks) {
                    half8v av = *(const half8v*)&H2[myrow * K2P + ks * 32 + qd * 8];
#pragma unroll
                    for (int mt = 0; mt < 8; ++mt)
                        acc3[mt] = __builtin_amdgcn_mfma_f32_16x16x32_f16(av, a3[ks][mt], acc3[mt], 0, 0, 0);
                }
                const short* np4 = &nbr_s[wv * 16 + qd * 4];
                const bool v0 = np4[0] >= 0, v1 = np4[1] >= 0;
                const bool v2 = np4[2] >= 0, v3 = np4[3] >= 0;
#pragma unroll
                for (int mt = 0; mt < 8; ++mt) {
                    float m = v0 ? acc3[mt][0] : -INFINITY;
                    m = fmaxf(m, v1 ? acc3[mt][1] : -INFINITY);
                    m = fmaxf(m, v2 ? acc3[mt][2] : -INFINITY);
                    m = fmaxf(m, v3 ? acc3[mt][3] : -INFINITY);
                    m = fmaxf(m, __shfl_xor(m, 16));
                    m = fmaxf(m, __shfl_xor(m, 32));
                    if (qd == 0) CW[wv * NCO + mt * 16 + c] = m;
                }
            }
        }
        __syncthreads();

        if (tid < NCO) {
            float m = fmaxf(fmaxf(CW[tid], CW[NCO + tid]),
                            fmaxf(CW[2 * NCO + tid], CW[3 * NCO + tid]));
            m += b3r;                                  // exact: add after max
            if (nbr_s[NK - 1] < 0) m = fmaxf(m, 0.f);  // ref's masked zeros
            out[(size_t)bs * NCO + tid] = m;
        }
        __syncthreads();   // protect nbr_s/G/CW before next query's ballq/gather
    }
}

extern "C" void kernel_launch(void* const* d_in, const int* in_sizes, int n_in,
                              void* d_out, int out_size, void* d_ws, size_t ws_size,
                              hipStream_t stream) {
    const float* x   = (const float*)d_in[0];
    const float* pos = (const float*)d_in[1];
    const float* W1  = (const float*)d_in[2];
    const float* b1  = (const float*)d_in[3];
    const float* W2  = (const float*)d_in[4];
    const float* b2  = (const float*)d_in[5];
    const float* W3  = (const float*)d_in[6];
    const float* b3  = (const float*)d_in[7];

    float* out0 = (float*)d_out;                        // [B,S,128]
    float* nxyz = out0 + (size_t)NB * NS * NCO;         // [B,S,3]
    int*      widxp = (int*)((char*)d_ws + WS_WIDX);    // tokens (0xAA poison < 0)
    _Float16* wtp   = (_Float16*)((char*)d_ws + WS_WT); // f16 weights, 40 KB

    wt_kernel<<<256, 64, 0, stream>>>(W1, W2, W3, wtp);
    fused_kernel<<<256, 512, 0, stream>>>(x, pos, b1, b2, b3, wtp,
                                          nxyz, out0, widxp);
}

// Round 15
// 742.078 us; speedup vs baseline: 1.1198x; 1.1198x over previous
//
#include <hip/hip_runtime.h>
#include <stdint.h>

#define NB 8
#define NP 4096
#define NS 1024
#define NK 64
#define ND 64
#define NH 64
#define NCO 128

#define PPT2 16            // producer: 4 waves x 256 threads x 16 points

// padded K strides (in halves) for conflict-free b128 LDS access
#define K1P 104            // layer1 K: 64 x-ch + 3 xyz + zeros to 96, padded to 104
#define K2P 72             // layer2/3 K: 64, padded to 72

// workspace layout (bytes)
#define WS_WIDX 0          // int[NB*NS] per-step winner index tokens (32 KB)
#define WS_WT   32768      // _Float16 weights (20480 halves = 40 KB)

typedef _Float16 half8v __attribute__((ext_vector_type(8)));
typedef _Float16 half4v __attribute__((ext_vector_type(4)));
typedef _Float16 half2v __attribute__((ext_vector_type(2)));
typedef float    floatx4 __attribute__((ext_vector_type(4)));

// DPP move helper (ctrl must be compile-time constant)
template <int CTRL>
__device__ __forceinline__ float dpp_mov_f32(float x) {
    return __int_as_float(__builtin_amdgcn_update_dpp(
        0, __float_as_int(x), CTRL, 0xf, 0xf, true));
}

// ---------------- Kernel 0: weight transpose + f16 convert ----------------
__global__ __launch_bounds__(64) void wt_kernel(const float* __restrict__ W1,
                                                const float* __restrict__ W2,
                                                const float* __restrict__ W3,
                                                _Float16* __restrict__ wt)
{
    const int j = blockIdx.x;
    const int t = threadIdx.x;
    if (j < 64) {
        for (int k = t; k < K1P; k += 64) {
            float v = 0.f;
            if (k < 64)       v = W1[(3 + k) * 64 + j];
            else if (k < 67)  v = W1[(k - 64) * 64 + j];
            wt[j * K1P + k] = (_Float16)v;
        }
    } else if (j < 128) {
        const int r = j - 64;
        for (int k = t; k < K2P; k += 64) {
            float v = (k < 64) ? W2[k * 64 + r] : 0.f;
            wt[6656 + r * K2P + k] = (_Float16)v;
        }
    } else {
        const int r = j - 128;
        for (int k = t; k < K2P; k += 64) {
            float v = (k < 64) ? W3[k * 128 + r] : 0.f;
            wt[11264 + r * K2P + k] = (_Float16)v;
        }
    }
}

// ---------------- Fused kernel: fps producers + ballq/mlp consumers ----------
// Grid = 256 blocks x 512 threads; all blocks co-resident (1/CU) => spin-wait
// deadlock-free. Blocks 0..7: fps with FOUR update waves (256 thr x 16 pts,
// bit-exact R6 arithmetic) — waves 4..7 only match the one barrier per step
// (instant arrival: halves the real barrier population and the key tree is
// 4-wide). Tokens latched in registers, flushed 16-wide per 16 steps (R10).
// Winner coords via broadcast sp[last] read — proven cheapest (R5/R14 both
// lost trying to replace it with register/cbuf paths).
// Blocks 8..255: consumers — token spin, single-wave ballq, MFMA mlp; they
// also write new_xyz from pos[token] (bit-identical to producer's sp rows).
__global__ __launch_bounds__(512, 2) void fused_kernel(
        const float* __restrict__ x, const float* __restrict__ pos,
        const float* __restrict__ b1v, const float* __restrict__ b2v,
        const float* __restrict__ b3v,
        const _Float16* __restrict__ wt,
        float* __restrict__ new_xyz, float* __restrict__ out, int* widx)
{
    __shared__ alignas(16) char smem[65664];
    const int tid  = threadIdx.x;
    const int lane = tid & 63;
    const int wv   = tid >> 6;

    if (blockIdx.x < NB) {
        // ================= FPS (4 update waves, R10 publish) =================
#pragma clang fp contract(off)
        const int b = blockIdx.x;
        float4* sp = (float4*)smem;                               // 64 KB
        unsigned long long* kbuf = (unsigned long long*)(smem + 65536); // [2][8]

        const float* p = pos + (size_t)b * NP * 3;
        for (int i = tid; i < NP; i += 512) {
            sp[i] = make_float4(p[i * 3 + 0], p[i * 3 + 1], p[i * 3 + 2], 0.0f);
        }
        __syncthreads();

        if (wv >= 4) {
            // barrier companions: one arrival per step, nothing else
            for (int s = 1; s < NS; ++s) __syncthreads();
            return;
        }

        float px[PPT2], py[PPT2], pz[PPT2], md[PPT2];
#pragma unroll
        for (int j = 0; j < PPT2; ++j) {
            float4 v = sp[tid * PPT2 + j];
            px[j] = v.x; py[j] = v.y; pz[j] = v.z;
            md[j] = 1e10f;
        }

        int last = 0;
        if (tid == 0) {   // s=0 token
            __hip_atomic_store(widx + b * NS, 0, __ATOMIC_RELAXED,
                               __HIP_MEMORY_SCOPE_AGENT);
        }
        int tok = 0;      // per-lane latched token (wave 0 lanes 0..15 flush)

        int par = 0;
        for (int s = 1; s < NS; ++s) {
            const float4 lp = sp[last];
            const float lx = lp.x, ly = lp.y, lz = lp.z;

            float bv = 0.0f;
            int   bi = tid * PPT2;
#pragma unroll
            for (int j = 0; j < PPT2; ++j) {
                float dx = px[j] - lx;
                float dy = py[j] - ly;
                float dz = pz[j] - lz;
                float d2 = dx * dx + dy * dy + dz * dz;  // contract(off): exact
                float m  = (md[j] < d2) ? md[j] : d2;    // jnp.minimum
                md[j] = m;
                if (m > bv) { bv = m; bi = tid * PPT2 + j; }
            }

            float r = bv;
            r = fmaxf(r, dpp_mov_f32<0x111>(r));   // row_shr:1
            r = fmaxf(r, dpp_mov_f32<0x112>(r));   // row_shr:2
            r = fmaxf(r, dpp_mov_f32<0x114>(r));   // row_shr:4
            r = fmaxf(r, dpp_mov_f32<0x118>(r));   // row_shr:8
            r = fmaxf(r, dpp_mov_f32<0x142>(r));   // row_bcast:15
            r = fmaxf(r, dpp_mov_f32<0x143>(r));   // row_bcast:31
            const float gmax = __int_as_float(
                __builtin_amdgcn_readlane(__float_as_int(r), 63));

            unsigned long long mk = __ballot(bv == gmax);
            int wl = (int)__builtin_ctzll(mk);
            int bw = __builtin_amdgcn_readlane(bi, wl);

            if (lane == 0) {
                kbuf[par * 8 + wv] =
                    ((unsigned long long)__float_as_uint(gmax) << 32) |
                    (unsigned long long)(~(unsigned)bw);
            }
            __syncthreads();

            // 4-key tree (2 b128 reads, 3 compares)
            const ulonglong2* wb = (const ulonglong2*)(kbuf + par * 8);
            ulonglong2 q0 = wb[0], q1 = wb[1];
            unsigned long long a0 = (q0.y > q0.x) ? q0.y : q0.x;
            unsigned long long a1 = (q1.y > q1.x) ? q1.y : q1.x;
            unsigned long long g  = (a1 > a0) ? a1 : a0;

            last = (int)(~(unsigned)g);

            // latch token in the matching lane (all threads know `last`)
            if ((s & 15) == lane) tok = last;
            // flush 16 tokens as one coalesced store per 16 steps
            if ((s & 15) == 15 && wv == 0 && lane < 16) {
                __hip_atomic_store(widx + b * NS + (s - 15) + lane, tok,
                                   __ATOMIC_RELAXED, __HIP_MEMORY_SCOPE_AGENT);
            }
            par ^= 1;
        }
        return;
    }

    // ================= Consumer: ballq + gather + MLP + pool =================
    const int ci = blockIdx.x - NB;   // 0..247
    const int b  = ci & 7;
    const int r0 = ci >> 3;           // 0..30

    _Float16* G   = (_Float16*)smem;            // 64*K1P halves = 13312 B
    _Float16* H1  = (_Float16*)(smem + 13312);  // 64*K2P = 9216 B
    _Float16* H2  = (_Float16*)(smem + 22528);  // 9216 B
    float*    CW  = (float*)(smem + 31744);     // 4*NCO = 2048 B
    float*    Lb  = (float*)(smem + 33792);     // 128 floats = 512 B
    short*  nbr_s = (short*)(smem + 34304);     // 128 B
    float*    qv  = (float*)(smem + 34432);     // 12 B

    const int qd = lane >> 4;         // quad
    const int c  = lane & 15;         // col within MFMA tile
    const int myrow = wv * 16 + c;    // neighbor row (waves 0-3 only)

    // weight frag hoist + bias staging (waves 0-3)
    half8v a1[3][4], a2[2][4], a3[2][8];
    float b3r = 0.f;
    if (tid < 256) {
#pragma unroll
        for (int ks = 0; ks < 3; ++ks)
#pragma unroll
            for (int mt = 0; mt < 4; ++mt)
                a1[ks][mt] = *(const half8v*)&wt[(mt * 16 + c) * K1P + ks * 32 + qd * 8];
#pragma unroll
        for (int ks = 0; ks < 2; ++ks)
#pragma unroll
            for (int mt = 0; mt < 4; ++mt)
                a2[ks][mt] = *(const half8v*)&wt[6656 + (mt * 16 + c) * K2P + ks * 32 + qd * 8];
#pragma unroll
        for (int ks = 0; ks < 2; ++ks)
#pragma unroll
            for (int mt = 0; mt < 8; ++mt)
                a3[ks][mt] = *(const half8v*)&wt[11264 + (mt * 16 + c) * K2P + ks * 32 + qd * 8];
        if (tid < 64) { Lb[tid] = b1v[tid]; Lb[64 + tid] = b2v[tid]; }
        if (tid < NCO) b3r = b3v[tid];
        half8v z = {};
        for (int i = tid; i < (64 * K1P) / 8; i += 256) ((half8v*)G)[i] = z;
    }

    for (int s = r0; s < NS; s += 31) {
        const int bs = b * NS + s;

        // ---- spin on the self-describing token (poison 0xAA.. < 0) ----
        int idx = -1, guard = 0;
        for (;;) {
            idx = __hip_atomic_load(widx + bs, __ATOMIC_RELAXED,
                                    __HIP_MEMORY_SCOPE_AGENT);
            if (idx >= 0) break;
            __builtin_amdgcn_s_sleep(8);
            if (++guard > (1 << 26)) break;   // escape hatch: fail loud, not hang
        }
        const int qidx = (idx >= 0 && idx < NP) ? idx : 0;

        // ---- wave 0: ball query into LDS (query coords from pos[qidx]);
        //      also writes this query's new_xyz (bit-identical to producer's) --
        if (wv == 0) {
#pragma clang fp contract(off)
            const float* p = pos + (size_t)b * NP * 3;
            const float qx = p[qidx * 3 + 0];
            const float qy = p[qidx * 3 + 1];
            const float qz = p[qidx * 3 + 2];
            if (lane == 0) {
                qv[0] = qx; qv[1] = qy; qv[2] = qz;
                float* o = new_xyz + (size_t)bs * 3;
                o[0] = qx; o[1] = qy; o[2] = qz;
            }
            int cnt = 0;
            for (int n0 = 0; n0 < NP; n0 += 64) {
                const int n = n0 + lane;
                float dx = qx - p[n * 3 + 0];
                float dy = qy - p[n * 3 + 1];
                float dz = qz - p[n * 3 + 2];
                float d2 = dx * dx + dy * dy + dz * dz;   // contract(off)
                bool within = d2 < 0.04f;                 // r^2, strict <
                unsigned long long m = __ballot(within);
                if (within) {
                    int slot = cnt + __popcll(m & ((1ull << lane) - 1ull));
                    if (slot < NK) nbr_s[slot] = (short)n;
                }
                cnt += (int)__popcll(m);
                if (cnt >= NK) break;
            }
            if (cnt < NK) {
                if (lane < NK - cnt) nbr_s[cnt + lane] = (short)-1;
            }
        }
        __syncthreads();   // nbr_s, qv ready

        // ---- gather (waves 0-3): thread -> neighbor tid>>2, channel quarter ----
        if (tid < 256) {
            const int ni = tid >> 2;
            const int p4 = tid & 3;
            const int n  = (int)nbr_s[ni];
            const int nn = (n < 0) ? (NP - 1) : n;    // ref: points[-1] padding
            const float* xr = x + ((size_t)b * NP + nn) * ND + p4 * 16;
#pragma unroll
            for (int i = 0; i < 4; ++i) {
                float4 v = *(const float4*)(xr + 4 * i);
                half4v h;
                h[0] = (_Float16)v.x; h[1] = (_Float16)v.y;
                h[2] = (_Float16)v.z; h[3] = (_Float16)v.w;
                *(half4v*)&G[ni * K1P + p4 * 16 + 4 * i] = h;
            }
            if (p4 == 0) {
                const float* pr = pos + (size_t)(b * NP + nn) * 3;
                float gx = pr[0] - qv[0];
                float gy = pr[1] - qv[1];
                float gz = pr[2] - qv[2];
                half2v h2; h2[0] = (_Float16)gx; h2[1] = (_Float16)gy;
                *(half2v*)&G[ni * K1P + 64] = h2;
                G[ni * K1P + 66] = (_Float16)gz;
            }
        }
        __syncthreads();

        if (tid < 256) {
            // ---- layer 1: K=96 (3 steps), out 64 ch ----
            {
                floatx4 acc[4] = {};
#pragma unroll
                for (int ks = 0; ks < 3; ++ks) {
                    half8v bf = *(const half8v*)&G[myrow * K1P + ks * 32 + qd * 8];
#pragma unroll
                    for (int mt = 0; mt < 4; ++mt)
                        acc[mt] = __builtin_amdgcn_mfma_f32_16x16x32_f16(a1[ks][mt], bf, acc[mt], 0, 0, 0);
                }
#pragma unroll
                for (int mt = 0; mt < 4; ++mt) {
                    float4 bb = *(const float4*)&Lb[mt * 16 + qd * 4];
                    half4v h;
                    h[0] = (_Float16)fmaxf(acc[mt][0] + bb.x, 0.f);
                    h[1] = (_Float16)fmaxf(acc[mt][1] + bb.y, 0.f);
                    h[2] = (_Float16)fmaxf(acc[mt][2] + bb.z, 0.f);
                    h[3] = (_Float16)fmaxf(acc[mt][3] + bb.w, 0.f);
                    *(half4v*)&H1[myrow * K2P + mt * 16 + qd * 4] = h;
                }
            }
            // ---- layer 2: K=64 (2 steps), out 64 ch ----
            {
                floatx4 acc[4] = {};
#pragma unroll
                for (int ks = 0; ks < 2; ++ks) {
                    half8v bf = *(const half8v*)&H1[myrow * K2P + ks * 32 + qd * 8];
#pragma unroll
                    for (int mt = 0; mt < 4; ++mt)
                        acc[mt] = __builtin_amdgcn_mfma_f32_16x16x32_f16(a2[ks][mt], bf, acc[mt], 0, 0, 0);
                }
#pragma unroll
                for (int mt = 0; mt < 4; ++mt) {
                    float4 bb = *(const float4*)&Lb[64 + mt * 16 + qd * 4];
                    half4v h;
                    h[0] = (_Float16)fmaxf(acc[mt][0] + bb.x, 0.f);
                    h[1] = (_Float16)fmaxf(acc[mt][1] + bb.y, 0.f);
                    h[2] = (_Float16)fmaxf(acc[mt][2] + bb.z, 0.f);
                    h[3] = (_Float16)fmaxf(acc[mt][3] + bb.w, 0.f);
                    *(half4v*)&H2[myrow * K2P + mt * 16 + qd * 4] = h;
                }
            }
            // ---- layer 3 (swapped operands): C rows = neighbors ----
            {
                floatx4 acc3[8] = {};
#pragma unroll
                for (int ks = 0; ks < 2; ++ks) {
                    half8v av = *(const half8v*)&H2[myrow * K2P + ks * 32 + qd * 8];
#pragma unroll
                    for (int mt = 0; mt < 8; ++mt)
                        acc3[mt] = __builtin_amdgcn_mfma_f32_16x16x32_f16(av, a3[ks][mt], acc3[mt], 0, 0, 0);
                }
                const short* np4 = &nbr_s[wv * 16 + qd * 4];
                const bool v0 = np4[0] >= 0, v1 = np4[1] >= 0;
                const bool v2 = np4[2] >= 0, v3 = np4[3] >= 0;
#pragma unroll
                for (int mt = 0; mt < 8; ++mt) {
                    float m = v0 ? acc3[mt][0] : -INFINITY;
                    m = fmaxf(m, v1 ? acc3[mt][1] : -INFINITY);
                    m = fmaxf(m, v2 ? acc3[mt][2] : -INFINITY);
                    m = fmaxf(m, v3 ? acc3[mt][3] : -INFINITY);
                    m = fmaxf(m, __shfl_xor(m, 16));
                    m = fmaxf(m, __shfl_xor(m, 32));
                    if (qd == 0) CW[wv * NCO + mt * 16 + c] = m;
                }
            }
        }
        __syncthreads();

        if (tid < NCO) {
            float m = fmaxf(fmaxf(CW[tid], CW[NCO + tid]),
                            fmaxf(CW[2 * NCO + tid], CW[3 * NCO + tid]));
            m += b3r;                                  // exact: add after max
            if (nbr_s[NK - 1] < 0) m = fmaxf(m, 0.f);  // ref's masked zeros
            out[(size_t)bs * NCO + tid] = m;
        }
        __syncthreads();   // protect nbr_s/G/CW before next query's ballq/gather
    }
}

extern "C" void kernel_launch(void* const* d_in, const int* in_sizes, int n_in,
                              void* d_out, int out_size, void* d_ws, size_t ws_size,
                              hipStream_t stream) {
    const float* x   = (const float*)d_in[0];
    const float* pos = (const float*)d_in[1];
    const float* W1  = (const float*)d_in[2];
    const float* b1  = (const float*)d_in[3];
    const float* W2  = (const float*)d_in[4];
    const float* b2  = (const float*)d_in[5];
    const float* W3  = (const float*)d_in[6];
    const float* b3  = (const float*)d_in[7];

    float* out0 = (float*)d_out;                        // [B,S,128]
    float* nxyz = out0 + (size_t)NB * NS * NCO;         // [B,S,3]
    int*      widxp = (int*)((char*)d_ws + WS_WIDX);    // tokens (0xAA poison < 0)
    _Float16* wtp   = (_Float16*)((char*)d_ws + WS_WT); // f16 weights, 40 KB

    wt_kernel<<<256, 64, 0, stream>>>(W1, W2, W3, wtp);
    fused_kernel<<<256, 512, 0, stream>>>(x, pos, b1, b2, b3, wtp,
                                          nxyz, out0, widxp);
}